// Round 2
// baseline (4930.385 us; speedup 1.0000x reference)
//
#include <hip/hip_runtime.h>
#include <hip/hip_bf16.h>
#include <math.h>

// Problem constants (fixed by the reference)
#define B_SZ 2
#define L_SEQ 4096
#define D_MODEL 1024
#define D_INNER 2048
#define D_STATE 64
#define DT_RANK 128
#define BL (B_SZ * L_SEQ)          // 8192 rows

// ---------------------------------------------------------------------------
// Generic fp32 GEMM: C[m,n] = act( sum_k A[m,k]*B[n,k] [+ bias[n]] )
// A: M x K row-major (lda), B: N x K row-major (ldb)  => C = A * B^T
// act: 0 = none, 1 = softplus (bias added first), 2 = silu
// Tile 128x128, BK=16, 256 threads, 8x8 per thread.
// ---------------------------------------------------------------------------
#define BM 128
#define BN 128
#define BK 16

__global__ __launch_bounds__(256) void gemm_abt(
    const float* __restrict__ A, int lda,
    const float* __restrict__ B, int ldb,
    float* __restrict__ C, int ldc,
    int K,
    const float* __restrict__ bias, int act)
{
    __shared__ float As[BK][BM + 4];
    __shared__ float Bs[BK][BN + 4];

    const int tid = threadIdx.x;
    const int bm = blockIdx.y * BM;
    const int bn = blockIdx.x * BN;
    const int tx = tid & 15;           // 0..15 -> col groups of 8
    const int ty = tid >> 4;           // 0..15 -> row groups of 8

    const int lr = tid >> 1;           // 0..127
    const int lc = (tid & 1) * 8;      // 0 or 8

    const float* Ag = A + (size_t)(bm + lr) * lda + lc;
    const float* Bg = B + (size_t)(bn + lr) * ldb + lc;

    float acc[8][8];
#pragma unroll
    for (int i = 0; i < 8; ++i)
#pragma unroll
        for (int j = 0; j < 8; ++j) acc[i][j] = 0.f;

    for (int k0 = 0; k0 < K; k0 += BK) {
        float4 a0 = *(const float4*)(Ag);
        float4 a1 = *(const float4*)(Ag + 4);
        float4 b0 = *(const float4*)(Bg);
        float4 b1 = *(const float4*)(Bg + 4);
        __syncthreads();   // previous-iteration LDS reads done before overwrite
        As[lc + 0][lr] = a0.x; As[lc + 1][lr] = a0.y;
        As[lc + 2][lr] = a0.z; As[lc + 3][lr] = a0.w;
        As[lc + 4][lr] = a1.x; As[lc + 5][lr] = a1.y;
        As[lc + 6][lr] = a1.z; As[lc + 7][lr] = a1.w;
        Bs[lc + 0][lr] = b0.x; Bs[lc + 1][lr] = b0.y;
        Bs[lc + 2][lr] = b0.z; Bs[lc + 3][lr] = b0.w;
        Bs[lc + 4][lr] = b1.x; Bs[lc + 5][lr] = b1.y;
        Bs[lc + 6][lr] = b1.z; Bs[lc + 7][lr] = b1.w;
        __syncthreads();

#pragma unroll
        for (int kk = 0; kk < BK; ++kk) {
            float a[8], b[8];
            *(float4*)(a + 0) = *(const float4*)&As[kk][ty * 8 + 0];
            *(float4*)(a + 4) = *(const float4*)&As[kk][ty * 8 + 4];
            *(float4*)(b + 0) = *(const float4*)&Bs[kk][tx * 8 + 0];
            *(float4*)(b + 4) = *(const float4*)&Bs[kk][tx * 8 + 4];
#pragma unroll
            for (int i = 0; i < 8; ++i)
#pragma unroll
                for (int j = 0; j < 8; ++j)
                    acc[i][j] = fmaf(a[i], b[j], acc[i][j]);
        }
        Ag += BK;
        Bg += BK;
    }

#pragma unroll
    for (int i = 0; i < 8; ++i) {
        float* crow = C + (size_t)(bm + ty * 8 + i) * ldc + bn + tx * 8;
        float v[8];
#pragma unroll
        for (int j = 0; j < 8; ++j) v[j] = acc[i][j];
        if (act == 1) {
#pragma unroll
            for (int j = 0; j < 8; ++j) {
                float t = v[j] + bias[bn + tx * 8 + j];
                v[j] = (t > 20.f) ? t : log1pf(__expf(t));
            }
        } else if (act == 2) {
#pragma unroll
            for (int j = 0; j < 8; ++j) v[j] = v[j] / (1.f + __expf(-v[j]));
        }
        *(float4*)(crow + 0) = *(const float4*)(v + 0);
        *(float4*)(crow + 4) = *(const float4*)(v + 4);
    }
}

// ---------------------------------------------------------------------------
// causal depthwise conv (k=4) + bias + silu.  x: [BL][2048] -> xc: [BL][2048]
// ---------------------------------------------------------------------------
__global__ __launch_bounds__(256) void conv_silu_kernel(
    const float* __restrict__ x,
    const float* __restrict__ w,      // [2048][4]
    const float* __restrict__ bias,   // [2048]
    float* __restrict__ xc)
{
    int idx = blockIdx.x * blockDim.x + threadIdx.x;   // 0 .. 8192*2048-1
    int d = idx & (D_INNER - 1);
    int m = idx >> 11;
    int l = m & (L_SEQ - 1);
    const float* xp = x + (size_t)m * D_INNER + d;
    float4 wv = ((const float4*)w)[d];
    float acc = bias[d];
    if (l >= 3) acc = fmaf(wv.x, xp[-3 * D_INNER], acc);
    if (l >= 2) acc = fmaf(wv.y, xp[-2 * D_INNER], acc);
    if (l >= 1) acc = fmaf(wv.z, xp[-1 * D_INNER], acc);
    acc = fmaf(wv.w, xp[0], acc);
    xc[idx] = acc / (1.f + __expf(-acc));
}

// ---------------------------------------------------------------------------
// selective scan: one wave per (b, d); lane = state index n (0..63)
//   h = h * exp(dt*A[d,n]) + (dt*x)*B[l,n];  y = sum_n h*C[l,n]
//   y_final = (y + D[d]*x) * silu_z   -> written in place over silu_z
// (in-place z read/y write is safe: the z load at step l precedes lane-0's
//  store at step l in wave-lockstep program order, and each address is
//  touched by exactly one wave)
// ---------------------------------------------------------------------------
__global__ __launch_bounds__(256) void scan_kernel(
    const float* __restrict__ dt,     // [BL][2048]
    const float* __restrict__ xc,     // [BL][2048]
    const float* __restrict__ xdbl,   // [BL][256]  (B at +128, C at +192)
    float* __restrict__ zy,           // [BL][2048]: silu(z) in, y out
    const float* __restrict__ A_log,  // [2048][64]
    const float* __restrict__ Dp)     // [2048]
{
    const int wid = threadIdx.x >> 6;
    const int lane = threadIdx.x & 63;
    const int gw = blockIdx.x * 4 + wid;   // 0..4095
    const int b = gw >> 11;
    const int d = gw & (D_INNER - 1);

    const float An = -__expf(A_log[d * D_STATE + lane]);
    const float Dd = Dp[d];

    size_t mbase = (size_t)b * L_SEQ;
    const float* dtp = dt   + mbase * D_INNER + d;
    const float* xp  = xc   + mbase * D_INNER + d;
    const float* bcp = xdbl + mbase * 256 + DT_RANK + lane;
    float*       zp  = zy   + mbase * D_INNER + d;

    float h = 0.f;
#pragma unroll 2
    for (int l = 0; l < L_SEQ; ++l) {
        float dtv = *dtp;
        float xv  = *xp;
        float zs  = *zp;
        float Bv  = bcp[0];
        float Cv  = bcp[D_STATE];
        float dA  = __expf(dtv * An);
        h = fmaf(h, dA, dtv * xv * Bv);
        float p = h * Cv;
        p += __shfl_xor(p, 32);
        p += __shfl_xor(p, 16);
        p += __shfl_xor(p, 8);
        p += __shfl_xor(p, 4);
        p += __shfl_xor(p, 2);
        p += __shfl_xor(p, 1);
        if (lane == 0) *zp = fmaf(Dd, xv, p) * zs;
        dtp += D_INNER; xp += D_INNER; bcp += 256;
        zp += D_INNER;
    }
}

// ---------------------------------------------------------------------------
extern "C" void kernel_launch(void* const* d_in, const int* in_sizes, int n_in,
                              void* d_out, int out_size, void* d_ws, size_t ws_size,
                              hipStream_t stream)
{
    const float* hs        = (const float*)d_in[0];  // [2,4096,1024]
    const float* in_proj_w = (const float*)d_in[1];  // [4096,1024]
    const float* conv_w    = (const float*)d_in[2];  // [2048,1,4]
    const float* conv_b    = (const float*)d_in[3];  // [2048]
    const float* x_proj_w  = (const float*)d_in[4];  // [256,2048]
    const float* dt_proj_w = (const float*)d_in[5];  // [2048,128]
    const float* dt_proj_b = (const float*)d_in[6];  // [2048]
    const float* A_log     = (const float*)d_in[7];  // [2048,64]
    const float* Dp        = (const float*)d_in[8];  // [2048]
    const float* out_proj_w= (const float*)d_in[9];  // [1024,2048]
    float* out = (float*)d_out;                      // [2,4096,1024]

    // workspace layout (209.7 MB total):
    //   xbuf [8192][2048] fp32 @ 0      : pre-conv x, then reused for dt
    //   zbuf [8192][2048] fp32 @ 64 MB  : silu(z), then y written in place
    //   xc   [8192][2048] fp32 @ 128 MB : post-conv x
    //   xdbl [8192][256]  fp32 @ 192 MB
    char* ws = (char*)d_ws;
    float* xbuf = (float*)ws;
    float* zbuf = (float*)(ws + (size_t)BL * D_INNER * 4);
    float* xc   = (float*)(ws + (size_t)2 * BL * D_INNER * 4);
    float* xdbl = (float*)(ws + (size_t)3 * BL * D_INNER * 4);

    dim3 blk(256);

    // 1) x = hs @ in_proj_w[:2048]^T        (8192 x 2048, K=1024)
    gemm_abt<<<dim3(D_INNER / BN, BL / BM), blk, 0, stream>>>(
        hs, D_MODEL, in_proj_w, D_MODEL, xbuf, D_INNER, D_MODEL, nullptr, 0);

    // 2) silu(z) = silu(hs @ in_proj_w[2048:]^T)
    gemm_abt<<<dim3(D_INNER / BN, BL / BM), blk, 0, stream>>>(
        hs, D_MODEL, in_proj_w + (size_t)D_INNER * D_MODEL, D_MODEL,
        zbuf, D_INNER, D_MODEL, nullptr, 2);

    // 3) xc = silu(conv(x) + b)
    conv_silu_kernel<<<(BL * D_INNER) / 256, blk, 0, stream>>>(xbuf, conv_w, conv_b, xc);

    // 4) xdbl = xc @ x_proj_w^T             (8192 x 256, K=2048)
    gemm_abt<<<dim3(256 / BN, BL / BM), blk, 0, stream>>>(
        xc, D_INNER, x_proj_w, D_INNER, xdbl, 256, D_INNER, nullptr, 0);

    // 5) dt = softplus(xdbl[:, :128] @ dt_proj_w^T + dt_proj_b) -> reuse xbuf
    gemm_abt<<<dim3(D_INNER / BN, BL / BM), blk, 0, stream>>>(
        xdbl, 256, dt_proj_w, DT_RANK, xbuf, D_INNER, DT_RANK, dt_proj_b, 1);

    // 6) selective scan -> y in place over silu(z) in zbuf
    scan_kernel<<<(B_SZ * D_INNER) / 4, blk, 0, stream>>>(xbuf, xc, xdbl, zbuf, A_log, Dp);

    // 7) out = y @ out_proj_w^T             (8192 x 1024, K=2048)
    gemm_abt<<<dim3(D_MODEL / BN, BL / BM), blk, 0, stream>>>(
        zbuf, D_INNER, out_proj_w, D_INNER, out, D_MODEL, D_INNER, nullptr, 0);
}

// Round 3
// 3169.777 us; speedup vs baseline: 1.5554x; 1.5554x over previous
//
#include <hip/hip_runtime.h>
#include <hip/hip_bf16.h>
#include <math.h>

// Problem constants (fixed by the reference)
#define B_SZ 2
#define L_SEQ 4096
#define D_MODEL 1024
#define D_INNER 2048
#define D_STATE 64
#define DT_RANK 128
#define BL (B_SZ * L_SEQ)          // 8192 rows

// ---------------------------------------------------------------------------
// Generic fp32 GEMM: C[m,n] = act( sum_k A[m,k]*B[n,k] [+ bias[n]] )
// A: M x K row-major (lda), B: N x K row-major (ldb)  => C = A * B^T
// act: 0 = none, 1 = softplus (bias added first), 2 = silu
// Tile 128x128, BK=16, 256 threads, 8x8 per thread.
// ---------------------------------------------------------------------------
#define BM 128
#define BN 128
#define BK 16

__global__ __launch_bounds__(256) void gemm_abt(
    const float* __restrict__ A, int lda,
    const float* __restrict__ B, int ldb,
    float* __restrict__ C, int ldc,
    int K,
    const float* __restrict__ bias, int act)
{
    __shared__ float As[BK][BM + 4];
    __shared__ float Bs[BK][BN + 4];

    const int tid = threadIdx.x;
    const int bm = blockIdx.y * BM;
    const int bn = blockIdx.x * BN;
    const int tx = tid & 15;           // 0..15 -> col groups of 8
    const int ty = tid >> 4;           // 0..15 -> row groups of 8

    const int lr = tid >> 1;           // 0..127
    const int lc = (tid & 1) * 8;      // 0 or 8

    const float* Ag = A + (size_t)(bm + lr) * lda + lc;
    const float* Bg = B + (size_t)(bn + lr) * ldb + lc;

    float acc[8][8];
#pragma unroll
    for (int i = 0; i < 8; ++i)
#pragma unroll
        for (int j = 0; j < 8; ++j) acc[i][j] = 0.f;

    for (int k0 = 0; k0 < K; k0 += BK) {
        float4 a0 = *(const float4*)(Ag);
        float4 a1 = *(const float4*)(Ag + 4);
        float4 b0 = *(const float4*)(Bg);
        float4 b1 = *(const float4*)(Bg + 4);
        __syncthreads();   // previous-iteration LDS reads done before overwrite
        As[lc + 0][lr] = a0.x; As[lc + 1][lr] = a0.y;
        As[lc + 2][lr] = a0.z; As[lc + 3][lr] = a0.w;
        As[lc + 4][lr] = a1.x; As[lc + 5][lr] = a1.y;
        As[lc + 6][lr] = a1.z; As[lc + 7][lr] = a1.w;
        Bs[lc + 0][lr] = b0.x; Bs[lc + 1][lr] = b0.y;
        Bs[lc + 2][lr] = b0.z; Bs[lc + 3][lr] = b0.w;
        Bs[lc + 4][lr] = b1.x; Bs[lc + 5][lr] = b1.y;
        Bs[lc + 6][lr] = b1.z; Bs[lc + 7][lr] = b1.w;
        __syncthreads();

#pragma unroll
        for (int kk = 0; kk < BK; ++kk) {
            float a[8], b[8];
            *(float4*)(a + 0) = *(const float4*)&As[kk][ty * 8 + 0];
            *(float4*)(a + 4) = *(const float4*)&As[kk][ty * 8 + 4];
            *(float4*)(b + 0) = *(const float4*)&Bs[kk][tx * 8 + 0];
            *(float4*)(b + 4) = *(const float4*)&Bs[kk][tx * 8 + 4];
#pragma unroll
            for (int i = 0; i < 8; ++i)
#pragma unroll
                for (int j = 0; j < 8; ++j)
                    acc[i][j] = fmaf(a[i], b[j], acc[i][j]);
        }
        Ag += BK;
        Bg += BK;
    }

#pragma unroll
    for (int i = 0; i < 8; ++i) {
        float* crow = C + (size_t)(bm + ty * 8 + i) * ldc + bn + tx * 8;
        float v[8];
#pragma unroll
        for (int j = 0; j < 8; ++j) v[j] = acc[i][j];
        if (act == 1) {
#pragma unroll
            for (int j = 0; j < 8; ++j) {
                float t = v[j] + bias[bn + tx * 8 + j];
                v[j] = (t > 20.f) ? t : log1pf(__expf(t));
            }
        } else if (act == 2) {
#pragma unroll
            for (int j = 0; j < 8; ++j) v[j] = v[j] / (1.f + __expf(-v[j]));
        }
        *(float4*)(crow + 0) = *(const float4*)(v + 0);
        *(float4*)(crow + 4) = *(const float4*)(v + 4);
    }
}

// ---------------------------------------------------------------------------
// causal depthwise conv (k=4) + bias + silu.  x: [BL][2048] -> xc: [BL][2048]
// ---------------------------------------------------------------------------
__global__ __launch_bounds__(256) void conv_silu_kernel(
    const float* __restrict__ x,
    const float* __restrict__ w,      // [2048][4]
    const float* __restrict__ bias,   // [2048]
    float* __restrict__ xc)
{
    int idx = blockIdx.x * blockDim.x + threadIdx.x;   // 0 .. 8192*2048-1
    int d = idx & (D_INNER - 1);
    int m = idx >> 11;
    int l = m & (L_SEQ - 1);
    const float* xp = x + (size_t)m * D_INNER + d;
    float4 wv = ((const float4*)w)[d];
    float acc = bias[d];
    if (l >= 3) acc = fmaf(wv.x, xp[-3 * D_INNER], acc);
    if (l >= 2) acc = fmaf(wv.y, xp[-2 * D_INNER], acc);
    if (l >= 1) acc = fmaf(wv.z, xp[-1 * D_INNER], acc);
    acc = fmaf(wv.w, xp[0], acc);
    xc[idx] = acc / (1.f + __expf(-acc));
}

// ---------------------------------------------------------------------------
// Chunked parallel selective scan.
// One block (16 waves, 1024 thr) per (b,d). lane = state n. wave = chunk of 256.
//   pass 1: per chunk, P = prod a, H = local scan from h=0  -> LDS
//   pass 2: compose across chunks (15 steps)                -> h0 per chunk
//   pass 3: re-run chunk from h0, y[l] = sum_n h*C; batched 4-step butterflies
// dt/x/z columns staged in LDS up front (bulk-parallel scattered loads).
// y written over silu(z) in zbuf (z already staged -> no aliasing hazard).
// ---------------------------------------------------------------------------
#define SCAN_WAVES 16
#define CL (L_SEQ / SCAN_WAVES)   // 256

__global__ __launch_bounds__(1024, 8) void scan_kernel(
    const float* __restrict__ dt,     // [BL][2048]
    const float* __restrict__ xc,     // [BL][2048]
    const float* __restrict__ xdbl,   // [BL][256]  (B at +128, C at +192)
    float* __restrict__ zy,           // [BL][2048]: silu(z) in, y out
    const float* __restrict__ A_log,  // [2048][64]
    const float* __restrict__ Dp)     // [2048]
{
    __shared__ float s_dt[L_SEQ];
    __shared__ float s_x[L_SEQ];
    __shared__ float s_z[L_SEQ];
    __shared__ float s_P[SCAN_WAVES][D_STATE];
    __shared__ float s_H[SCAN_WAVES][D_STATE];

    const int bd  = blockIdx.x;            // 0..4095
    const int b   = bd >> 11;
    const int d   = bd & (D_INNER - 1);
    const int tid = threadIdx.x;
    const int wid = tid >> 6;
    const int lane = tid & 63;

    const size_t base = (size_t)b * L_SEQ * D_INNER + d;

    // stage the three columns (scattered loads, all in flight in parallel)
    for (int l = tid; l < L_SEQ; l += 1024) {
        size_t idx = base + (size_t)l * D_INNER;
        s_dt[l] = dt[idx];
        s_x[l]  = xc[idx];
        s_z[l]  = zy[idx];
    }

    const float An = -__expf(A_log[d * D_STATE + lane]);
    const float Dd = Dp[d];
    __syncthreads();

    // ---- pass 1: local chunk scan ----
    const int l0 = wid * CL;
    const float* bc = xdbl + ((size_t)b * L_SEQ + l0) * 256 + DT_RANK + lane;
    float P = 1.f, H = 0.f;
#pragma unroll 4
    for (int l = 0; l < CL; ++l) {
        float dtv = s_dt[l0 + l];
        float a = __expf(dtv * An);
        H = fmaf(H, a, dtv * s_x[l0 + l] * bc[0]);
        P *= a;
        bc += 256;
    }
    s_P[wid][lane] = P;
    s_H[wid][lane] = H;
    __syncthreads();

    // ---- pass 2: compose prefixes (h_start for this chunk) ----
    float h = 0.f;
    for (int c = 0; c < wid; ++c)
        h = fmaf(h, s_P[c][lane], s_H[c][lane]);

    // ---- pass 3: recompute with y output, 4-step batches for shuffle ILP ----
    float* yp = zy + base + (size_t)l0 * D_INNER;
    bc = xdbl + ((size_t)b * L_SEQ + l0) * 256 + DT_RANK + lane;
    for (int t0 = 0; t0 < CL; t0 += 4) {
        float Bv[4], Cv[4];
#pragma unroll
        for (int t = 0; t < 4; ++t) {
            Bv[t] = bc[0];
            Cv[t] = bc[D_STATE];
            bc += 256;
        }
        float p[4], xv[4];
#pragma unroll
        for (int t = 0; t < 4; ++t) {
            float dtv = s_dt[l0 + t0 + t];
            xv[t] = s_x[l0 + t0 + t];
            float a = __expf(dtv * An);
            h = fmaf(h, a, dtv * xv[t] * Bv[t]);
            p[t] = h * Cv[t];
        }
#pragma unroll
        for (int t = 0; t < 4; ++t) {
            p[t] += __shfl_xor(p[t], 32);
            p[t] += __shfl_xor(p[t], 16);
            p[t] += __shfl_xor(p[t], 8);
            p[t] += __shfl_xor(p[t], 4);
            p[t] += __shfl_xor(p[t], 2);
            p[t] += __shfl_xor(p[t], 1);
        }
        if (lane == 0) {
#pragma unroll
            for (int t = 0; t < 4; ++t)
                yp[(size_t)(t0 + t) * D_INNER] =
                    fmaf(Dd, xv[t], p[t]) * s_z[l0 + t0 + t];
        }
    }
}

// ---------------------------------------------------------------------------
extern "C" void kernel_launch(void* const* d_in, const int* in_sizes, int n_in,
                              void* d_out, int out_size, void* d_ws, size_t ws_size,
                              hipStream_t stream)
{
    const float* hs        = (const float*)d_in[0];  // [2,4096,1024]
    const float* in_proj_w = (const float*)d_in[1];  // [4096,1024]
    const float* conv_w    = (const float*)d_in[2];  // [2048,1,4]
    const float* conv_b    = (const float*)d_in[3];  // [2048]
    const float* x_proj_w  = (const float*)d_in[4];  // [256,2048]
    const float* dt_proj_w = (const float*)d_in[5];  // [2048,128]
    const float* dt_proj_b = (const float*)d_in[6];  // [2048]
    const float* A_log     = (const float*)d_in[7];  // [2048,64]
    const float* Dp        = (const float*)d_in[8];  // [2048]
    const float* out_proj_w= (const float*)d_in[9];  // [1024,2048]
    float* out = (float*)d_out;                      // [2,4096,1024]

    // workspace layout (209.7 MB total):
    //   xbuf [8192][2048] fp32 @ 0      : pre-conv x, then reused for dt
    //   zbuf [8192][2048] fp32 @ 64 MB  : silu(z), then y written in place
    //   xc   [8192][2048] fp32 @ 128 MB : post-conv x
    //   xdbl [8192][256]  fp32 @ 192 MB
    char* ws = (char*)d_ws;
    float* xbuf = (float*)ws;
    float* zbuf = (float*)(ws + (size_t)BL * D_INNER * 4);
    float* xc   = (float*)(ws + (size_t)2 * BL * D_INNER * 4);
    float* xdbl = (float*)(ws + (size_t)3 * BL * D_INNER * 4);

    dim3 blk(256);

    // 1) x = hs @ in_proj_w[:2048]^T        (8192 x 2048, K=1024)
    gemm_abt<<<dim3(D_INNER / BN, BL / BM), blk, 0, stream>>>(
        hs, D_MODEL, in_proj_w, D_MODEL, xbuf, D_INNER, D_MODEL, nullptr, 0);

    // 2) silu(z) = silu(hs @ in_proj_w[2048:]^T)
    gemm_abt<<<dim3(D_INNER / BN, BL / BM), blk, 0, stream>>>(
        hs, D_MODEL, in_proj_w + (size_t)D_INNER * D_MODEL, D_MODEL,
        zbuf, D_INNER, D_MODEL, nullptr, 2);

    // 3) xc = silu(conv(x) + b)
    conv_silu_kernel<<<(BL * D_INNER) / 256, blk, 0, stream>>>(xbuf, conv_w, conv_b, xc);

    // 4) xdbl = xc @ x_proj_w^T             (8192 x 256, K=2048)
    gemm_abt<<<dim3(256 / BN, BL / BM), blk, 0, stream>>>(
        xc, D_INNER, x_proj_w, D_INNER, xdbl, 256, D_INNER, nullptr, 0);

    // 5) dt = softplus(xdbl[:, :128] @ dt_proj_w^T + dt_proj_b) -> reuse xbuf
    gemm_abt<<<dim3(D_INNER / BN, BL / BM), blk, 0, stream>>>(
        xdbl, 256, dt_proj_w, DT_RANK, xbuf, D_INNER, DT_RANK, dt_proj_b, 1);

    // 6) chunked parallel scan -> y in place over silu(z) in zbuf
    scan_kernel<<<B_SZ * D_INNER, dim3(1024), 0, stream>>>(
        xbuf, xc, xdbl, zbuf, A_log, Dp);

    // 7) out = y @ out_proj_w^T             (8192 x 1024, K=2048)
    gemm_abt<<<dim3(D_MODEL / BN, BL / BM), blk, 0, stream>>>(
        zbuf, D_INNER, out_proj_w, D_INNER, out, D_MODEL, D_INNER, nullptr, 0);
}